// Round 3
// baseline (1130.786 us; speedup 1.0000x reference)
//
#include <hip/hip_runtime.h>
#include <hip/hip_cooperative_groups.h>
#include <math.h>

namespace cg = cooperative_groups;

#define H  256
#define KT 32

struct Params {
    const int *word_ids, *left_idx, *right_idx;
    const float *emb;
    const float *Wi, *bi, *Wo, *bo, *Wu, *bu;
    const float *Ui, *bui, *Uo, *buo, *Uu, *buu;
    const float *Uf1, *bf1, *Uf2, *bf2, *Wp, *bp;
    float *h_buf;   // [n_nodes][H]
    float *part;    // [n_internal][16][4][H]
    float *partL;   // [n_leaves][8][3][H]
    int   *cnt;     // [n_nodes]
    float *out;     // [n_nodes][5]
    int n_leaves, n_internal, n_nodes;
};

__device__ __forceinline__ float sigmoidf_(float x) {
    return 1.0f / (1.0f + expf(-x));
}

// winner-block projection for one node: out[node][0..4] = bp + Wp @ h
__device__ __forceinline__ void proj_node(const Params& P, int node, float h,
                                          int tid, float (*s_red)[5])
{
    const int j = tid;
    float p0 = P.Wp[0 * H + j] * h;
    float p1 = P.Wp[1 * H + j] * h;
    float p2 = P.Wp[2 * H + j] * h;
    float p3 = P.Wp[3 * H + j] * h;
    float p4 = P.Wp[4 * H + j] * h;
#pragma unroll
    for (int off = 32; off >= 1; off >>= 1) {
        p0 += __shfl_down(p0, off);
        p1 += __shfl_down(p1, off);
        p2 += __shfl_down(p2, off);
        p3 += __shfl_down(p3, off);
        p4 += __shfl_down(p4, off);
    }
    int lane = tid & 63, wv = tid >> 6;
    if (lane == 0) {
        s_red[wv][0] = p0; s_red[wv][1] = p1; s_red[wv][2] = p2;
        s_red[wv][3] = p3; s_red[wv][4] = p4;
    }
    __syncthreads();
    if (tid < 5)
        P.out[(size_t)node * 5 + tid] =
            P.bp[tid] + s_red[0][tid] + s_red[1][tid] + s_red[2][tid] + s_red[3][tid];
    __syncthreads();
}

__global__ __launch_bounds__(256, 2) void tree_kernel(Params P)
{
    cg::grid_group grid = cg::this_grid();
    const int tid = threadIdx.x;
    const int b   = blockIdx.x;
    const int G   = gridDim.x;
    const int j   = tid;

    __shared__ int   s_win[128];
    __shared__ float s_red[4][5];

    // ---------- phase 0: zero per-node counters ----------
    for (int i = b * 256 + tid; i < P.n_nodes; i += G * 256) P.cnt[i] = 0;
    grid.sync();

    float wA[KT], wB[KT], wC[KT], wD[KT];

    // ---------- leaf phase: k-split 8, partial -> count -> winner finalize ----------
    {
        const int NLC = G >> 3;           // leaf cohorts
        const int ktl = b & 7;            // this block's k-tile
        const int lco = b >> 3;           // this block's cohort
        const int k0  = ktl * KT;
        const float4* q0 = (const float4*)(P.Wi + (size_t)j * H + k0);
        const float4* q1 = (const float4*)(P.Wo + (size_t)j * H + k0);
        const float4* q2 = (const float4*)(P.Wu + (size_t)j * H + k0);
#pragma unroll
        for (int q = 0; q < KT / 4; ++q) {
            float4 v0 = q0[q], v1 = q1[q], v2 = q2[q];
            wA[4*q] = v0.x; wA[4*q+1] = v0.y; wA[4*q+2] = v0.z; wA[4*q+3] = v0.w;
            wB[4*q] = v1.x; wB[4*q+1] = v1.y; wB[4*q+2] = v1.z; wB[4*q+3] = v1.w;
            wC[4*q] = v2.x; wC[4*q+1] = v2.y; wC[4*q+2] = v2.z; wC[4*q+3] = v2.w;
        }
        for (int base = lco; base < P.n_leaves; base += NLC * 128) {
            int nit = 0;
            for (int it = 0; it < 128; ++it) {
                int l = base + it * NLC;
                if (l >= P.n_leaves) break;
                ++nit;
                int wid = __builtin_amdgcn_readfirstlane(P.word_ids[l]);
                const float* row = P.emb + (size_t)wid * H + k0;
                float a0 = 0.f, a1 = 0.f, a2 = 0.f;
#pragma unroll
                for (int kk = 0; kk < KT; ++kk) {
                    float x = row[kk];
                    a0 = fmaf(x, wA[kk], a0);
                    a1 = fmaf(x, wB[kk], a1);
                    a2 = fmaf(x, wC[kk], a2);
                }
                float* p = P.partL + (((size_t)l * 8 + ktl) * 3) * H + j;
                p[0]     = a0;
                p[H]     = a1;
                p[2 * H] = a2;
            }
            __threadfence();
            __syncthreads();
            if (tid < nit) {
                int l = base + tid * NLC;
                int old = atomicAdd(&P.cnt[l], 1);
                s_win[tid] = (old == 7) ? 1 : 0;
            }
            __syncthreads();
            bool fenced = false;
            for (int it = 0; it < nit; ++it) {
                if (!s_win[it]) continue;
                if (!fenced) { __threadfence(); fenced = true; }
                int l = base + it * NLC;
                const float* p = P.partL + ((size_t)l * 8 * 3) * H + j;
                float ai = P.bi[j], ao = P.bo[j], au = P.bu[j];
#pragma unroll
                for (int k2 = 0; k2 < 8; ++k2) {
                    const float* q = p + (size_t)k2 * 3 * H;
                    ai += q[0];
                    ao += q[H];
                    au += q[2 * H];
                }
                float ii = sigmoidf_(ai);
                float oo = sigmoidf_(ao);
                float uu = fmaxf(au, 0.f);
                float c  = ii * uu;
                float h  = oo * fmaxf(c, 0.f);
                P.h_buf[(size_t)l * H + j] = h;
                proj_node(P, l, h, tid, s_red);
            }
            __syncthreads();
        }
    }
    grid.sync();

    // ---------- internal levels: k-split 16, one grid.sync per level ----------
    {
        const int kt  = b & 15;
        const int coh = b >> 4;
        const int NC  = G >> 4;
        const int k0  = (kt & 7) * KT;
        const float4* q0 = (const float4*)(P.Ui + (size_t)j * 2 * H + kt * KT);
        const float4* q1 = (const float4*)(P.Uo + (size_t)j * 2 * H + kt * KT);
        const float4* q2 = (const float4*)(P.Uu + (size_t)j * 2 * H + kt * KT);
        const float*  fsrc = (kt < 8) ? P.Uf1 : P.Uf2;
        const float4* q3 = (const float4*)(fsrc + (size_t)j * H + k0);
#pragma unroll
        for (int q = 0; q < KT / 4; ++q) {
            float4 v0 = q0[q], v1 = q1[q], v2 = q2[q], v3 = q3[q];
            wA[4*q] = v0.x; wA[4*q+1] = v0.y; wA[4*q+2] = v0.z; wA[4*q+3] = v0.w;
            wB[4*q] = v1.x; wB[4*q+1] = v1.y; wB[4*q+2] = v1.z; wB[4*q+3] = v1.w;
            wC[4*q] = v2.x; wC[4*q+1] = v2.y; wC[4*q+2] = v2.z; wC[4*q+3] = v2.w;
            wD[4*q] = v3.x; wD[4*q+1] = v3.y; wD[4*q+2] = v3.z; wD[4*q+3] = v3.w;
        }
        const int* cidx = (kt < 8) ? P.left_idx : P.right_idx;

        int frontier = P.n_leaves;
        int tbase = 0;
        while (frontier > 1) {
            int lvl = frontier >> 1;
            for (int base = 0; base < lvl; base += NC * 128) {
                int nit = 0;
                for (int it = 0; it < 128; ++it) {
                    int t = tbase + base + coh + it * NC;
                    if (base + coh + it * NC >= lvl) break;
                    ++nit;
                    int child = __builtin_amdgcn_readfirstlane(cidx[t]);
                    const float* row = P.h_buf + (size_t)child * H + k0;
                    float a0 = 0.f, a1 = 0.f, a2 = 0.f, a3 = 0.f;
#pragma unroll
                    for (int kk = 0; kk < KT; ++kk) {
                        float x = row[kk];
                        a0 = fmaf(x, wA[kk], a0);
                        a1 = fmaf(x, wB[kk], a1);
                        a2 = fmaf(x, wC[kk], a2);
                        a3 = fmaf(x, wD[kk], a3);
                    }
                    float* p = P.part + (((size_t)t * 16 + kt) * 4) * H + j;
                    p[0]     = a0;
                    p[H]     = a1;
                    p[2 * H] = a2;
                    p[3 * H] = a3;
                }
                __threadfence();
                __syncthreads();
                if (tid < nit) {
                    int t = tbase + base + coh + tid * NC;
                    int old = atomicAdd(&P.cnt[P.n_leaves + t], 1);
                    s_win[tid] = (old == 15) ? 1 : 0;
                }
                __syncthreads();
                bool fenced = false;
                for (int it = 0; it < nit; ++it) {
                    if (!s_win[it]) continue;
                    if (!fenced) { __threadfence(); fenced = true; }
                    int t = tbase + base + coh + it * NC;
                    const float* p = P.part + ((size_t)t * 16 * 4) * H + j;
                    float ai = P.bui[j], ao = P.buo[j], au = P.buu[j];
                    float f1 = P.bf1[j], f2 = P.bf2[j];
#pragma unroll
                    for (int k2 = 0; k2 < 16; ++k2) {
                        const float* q = p + (size_t)k2 * 4 * H;
                        ai += q[0];
                        ao += q[H];
                        au += q[2 * H];
                        float fv = q[3 * H];
                        if (k2 < 8) f1 += fv; else f2 += fv;
                    }
                    int li = P.left_idx[t], ri = P.right_idx[t];
                    float lh = P.h_buf[(size_t)li * H + j];
                    float rh = P.h_buf[(size_t)ri * H + j];
                    float ii  = sigmoidf_(ai);
                    float oo  = sigmoidf_(ao);
                    float uu  = fmaxf(au, 0.f);
                    float ff1 = sigmoidf_(f1);
                    float ff2 = sigmoidf_(f2);
                    float c   = ii * uu + ff1 * lh + ff2 * rh;
                    float h   = oo * fmaxf(c, 0.f);
                    int node  = P.n_leaves + t;
                    P.h_buf[(size_t)node * H + j] = h;
                    proj_node(P, node, h, tid, s_red);
                }
                __syncthreads();
            }
            grid.sync();
            tbase += lvl;
            frontier = lvl + (frontier & 1);
        }
    }
}

extern "C" void kernel_launch(void* const* d_in, const int* in_sizes, int n_in,
                              void* d_out, int out_size, void* d_ws, size_t ws_size,
                              hipStream_t stream)
{
    Params P;
    P.word_ids  = (const int*)d_in[0];
    P.left_idx  = (const int*)d_in[1];
    P.right_idx = (const int*)d_in[2];
    P.emb = (const float*)d_in[3];
    P.Wi  = (const float*)d_in[4];  P.bi  = (const float*)d_in[5];
    P.Wo  = (const float*)d_in[6];  P.bo  = (const float*)d_in[7];
    P.Wu  = (const float*)d_in[8];  P.bu  = (const float*)d_in[9];
    P.Ui  = (const float*)d_in[10]; P.bui = (const float*)d_in[11];
    P.Uo  = (const float*)d_in[12]; P.buo = (const float*)d_in[13];
    P.Uu  = (const float*)d_in[14]; P.buu = (const float*)d_in[15];
    P.Uf1 = (const float*)d_in[16]; P.bf1 = (const float*)d_in[17];
    P.Uf2 = (const float*)d_in[18]; P.bf2 = (const float*)d_in[19];
    P.Wp  = (const float*)d_in[20]; P.bp  = (const float*)d_in[21];
    P.n_leaves   = in_sizes[0];
    P.n_internal = in_sizes[1];
    P.n_nodes    = P.n_leaves + P.n_internal;
    P.out = (float*)d_out;
    (void)n_in; (void)out_size; (void)ws_size;

    float* ws = (float*)d_ws;
    P.h_buf = ws;
    P.part  = P.h_buf + (size_t)P.n_nodes * H;
    P.partL = P.part  + (size_t)P.n_internal * 16 * 4 * H;
    P.cnt   = (int*)(P.partL + (size_t)P.n_leaves * 8 * 3 * H);

    // adaptive cooperative grid size (host-side queries: capture-time only)
    int dev = 0;
    hipGetDevice(&dev);
    hipDeviceProp_t props;
    hipGetDeviceProperties(&props, dev);
    int perCU = 0;
    hipOccupancyMaxActiveBlocksPerMultiprocessor(&perCU, (const void*)tree_kernel, 256, 0);
    if (perCU < 1) perCU = 1;
    long Gl = (long)perCU * props.multiProcessorCount;
    int G = (Gl > 512) ? 512 : (int)Gl;
    G &= ~15;                 // multiple of 16 (and of 8)
    if (G < 16) G = 16;

    void* args[] = { &P };
    hipLaunchCooperativeKernel((void*)tree_kernel, dim3(G), dim3(256), args, 0, stream);
}

// Round 4
// 695.578 us; speedup vs baseline: 1.6257x; 1.6257x over previous
//
#include <hip/hip_runtime.h>
#include <hip/hip_cooperative_groups.h>
#include <math.h>

namespace cg = cooperative_groups;

#define H 256

struct Params {
    const int *word_ids, *left_idx, *right_idx;
    const float *emb;
    const float *Wi, *bi, *Wo, *bo, *Wu, *bu;
    const float *Ui, *bui, *Uo, *buo, *Uu, *buu;
    const float *Uf1, *bf1, *Uf2, *bf2, *Wp, *bp;
    float *h_buf;   // [n_nodes][H]
    float *part;    // [n_internal][16][4][H]
    float *out;     // [n_nodes][5]
    int n_leaves, n_internal, n_nodes;
};

__device__ __forceinline__ float sigmoidf_(float x) {
    return 1.0f / (1.0f + expf(-x));
}

// per-node projection: out[node][0..4] = bp + Wp @ h  (block-wide, h = this thread's element)
__device__ __forceinline__ void proj_node(const Params& P, int node, float h,
                                          int tid, float (*s_red)[5])
{
    const int j = tid;
    float p0 = P.Wp[0 * H + j] * h;
    float p1 = P.Wp[1 * H + j] * h;
    float p2 = P.Wp[2 * H + j] * h;
    float p3 = P.Wp[3 * H + j] * h;
    float p4 = P.Wp[4 * H + j] * h;
#pragma unroll
    for (int off = 32; off >= 1; off >>= 1) {
        p0 += __shfl_down(p0, off);
        p1 += __shfl_down(p1, off);
        p2 += __shfl_down(p2, off);
        p3 += __shfl_down(p3, off);
        p4 += __shfl_down(p4, off);
    }
    int lane = tid & 63, wv = tid >> 6;
    if (lane == 0) {
        s_red[wv][0] = p0; s_red[wv][1] = p1; s_red[wv][2] = p2;
        s_red[wv][3] = p3; s_red[wv][4] = p4;
    }
    __syncthreads();
    if (tid < 5)
        P.out[(size_t)node * 5 + tid] =
            P.bp[tid] + s_red[0][tid] + s_red[1][tid] + s_red[2][tid] + s_red[3][tid];
    __syncthreads();
}

__global__ __launch_bounds__(256, 1) void tree_kernel(Params P)
{
    cg::grid_group grid = cg::this_grid();
    const int tid = threadIdx.x;
    const int b   = blockIdx.x;
    const int G   = gridDim.x;

    __shared__ float s_leaf[8][3][32];
    __shared__ float s_r[8][32];
    __shared__ float s_h[32];
    __shared__ float s_red[4][5];

    const int jj = tid & 31;
    const int hi = tid >> 5;     // [0,8)

    // ================= leaf phase: in-block k-split, register weights =================
    {
        const int jg   = b & 7;
        const int coh  = b >> 3;
        const int NCOH = G >> 3;
        const int jrow = jg * 32 + jj;          // weight row this thread serves
        float w3[3][32];
        {
            const float4* p0 = (const float4*)(P.Wi + (size_t)jrow * H + hi * 32);
            const float4* p1 = (const float4*)(P.Wo + (size_t)jrow * H + hi * 32);
            const float4* p2 = (const float4*)(P.Wu + (size_t)jrow * H + hi * 32);
#pragma unroll
            for (int q = 0; q < 8; ++q) {
                float4 v0 = p0[q], v1 = p1[q], v2 = p2[q];
                w3[0][4*q]=v0.x; w3[0][4*q+1]=v0.y; w3[0][4*q+2]=v0.z; w3[0][4*q+3]=v0.w;
                w3[1][4*q]=v1.x; w3[1][4*q+1]=v1.y; w3[1][4*q+2]=v1.z; w3[1][4*q+3]=v1.w;
                w3[2][4*q]=v2.x; w3[2][4*q+1]=v2.y; w3[2][4*q+2]=v2.z; w3[2][4*q+3]=v2.w;
            }
#pragma unroll
            for (int g = 0; g < 3; ++g)
#pragma unroll
                for (int m = 0; m < 32; ++m)
                    asm volatile("" : "+v"(w3[g][m]));   // pin: no remat/respill
        }
        for (int l = coh; l < P.n_leaves; l += NCOH) {
            int wid = __builtin_amdgcn_readfirstlane(P.word_ids[l]);
            const float4* er = (const float4*)(P.emb + (size_t)wid * H + hi * 32);
            float a0 = 0.f, a1 = 0.f, a2 = 0.f;
#pragma unroll
            for (int q = 0; q < 8; ++q) {
                float4 e4 = er[q];
                float ev0 = e4.x, ev1 = e4.y, ev2 = e4.z, ev3 = e4.w;
                a0 = fmaf(ev0, w3[0][4*q],   a0); a1 = fmaf(ev0, w3[1][4*q],   a1); a2 = fmaf(ev0, w3[2][4*q],   a2);
                a0 = fmaf(ev1, w3[0][4*q+1], a0); a1 = fmaf(ev1, w3[1][4*q+1], a1); a2 = fmaf(ev1, w3[2][4*q+1], a2);
                a0 = fmaf(ev2, w3[0][4*q+2], a0); a1 = fmaf(ev2, w3[1][4*q+2], a1); a2 = fmaf(ev2, w3[2][4*q+2], a2);
                a0 = fmaf(ev3, w3[0][4*q+3], a0); a1 = fmaf(ev3, w3[1][4*q+3], a1); a2 = fmaf(ev3, w3[2][4*q+3], a2);
            }
            s_leaf[hi][0][jj] = a0;
            s_leaf[hi][1][jj] = a1;
            s_leaf[hi][2][jj] = a2;
            __syncthreads();
            if (tid < 32) {
                int jo = jg * 32 + tid;
                float ai = 0.f, ao = 0.f, au = 0.f;
#pragma unroll
                for (int s = 0; s < 8; ++s) {
                    ai += s_leaf[s][0][tid];
                    ao += s_leaf[s][1][tid];
                    au += s_leaf[s][2][tid];
                }
                float ii = sigmoidf_(ai + P.bi[jo]);
                float oo = sigmoidf_(ao + P.bo[jo]);
                float uu = fmaxf(au + P.bu[jo], 0.f);
                float c  = ii * uu;
                float h  = oo * fmaxf(c, 0.f);
                P.h_buf[(size_t)l * H + jo] = h;
            }
            __syncthreads();
        }
    }
    grid.sync();

    // ================= internal levels: register U-slice, fused reduce-in-consumer =================
    {
        const int kt   = b & 15;
        const int coh  = b >> 4;
        const int NCOH = G >> 4;
        const int js   = (kt & 7) * 32;
        const int* cidx = (kt < 8) ? P.left_idx : P.right_idx;

        float w4[4][32];
        {
            const float4* p0 = (const float4*)(P.Ui + (size_t)tid * 2 * H + kt * 32);
            const float4* p1 = (const float4*)(P.Uo + (size_t)tid * 2 * H + kt * 32);
            const float4* p2 = (const float4*)(P.Uu + (size_t)tid * 2 * H + kt * 32);
            const float*  fsrc = (kt < 8) ? P.Uf1 : P.Uf2;
            const float4* p3 = (const float4*)(fsrc + (size_t)tid * H + js);
#pragma unroll
            for (int q = 0; q < 8; ++q) {
                float4 v0 = p0[q], v1 = p1[q], v2 = p2[q], v3 = p3[q];
                w4[0][4*q]=v0.x; w4[0][4*q+1]=v0.y; w4[0][4*q+2]=v0.z; w4[0][4*q+3]=v0.w;
                w4[1][4*q]=v1.x; w4[1][4*q+1]=v1.y; w4[1][4*q+2]=v1.z; w4[1][4*q+3]=v1.w;
                w4[2][4*q]=v2.x; w4[2][4*q+1]=v2.y; w4[2][4*q+2]=v2.z; w4[2][4*q+3]=v2.w;
                w4[3][4*q]=v3.x; w4[3][4*q+1]=v3.y; w4[3][4*q+2]=v3.z; w4[3][4*q+3]=v3.w;
            }
#pragma unroll
            for (int g = 0; g < 4; ++g)
#pragma unroll
                for (int m = 0; m < 32; ++m)
                    asm volatile("" : "+v"(w4[g][m]));   // pin: no remat/respill
        }

        const int g_  = hi & 3;
        const int kh_ = hi >> 2;

        int lvl = P.n_leaves >> 1;
        int tbase = 0, prev0 = 0, prev1 = 0;
        while (lvl >= 1) {
            for (int idx = coh; idx < lvl; idx += NCOH) {
                const int t = tbase + idx;
                const int c = __builtin_amdgcn_readfirstlane(cidx[t]);
                const int ctl = c - P.n_leaves;
                if (ctl >= prev0 && ctl < prev1) {
                    // fresh child: reduce its 16 kt-partials for my j-slice
                    const float* pc = P.part + (size_t)ctl * (64 * H)
                                      + ((kh_ * 8) * 4 + g_) * H + js + jj;
                    float acc = 0.f;
#pragma unroll
                    for (int m = 0; m < 8; ++m) acc += pc[m * 4 * H];
                    s_r[hi][jj] = acc;
                    __syncthreads();
                    if (tid < 32) {
                        const int jo = js + tid;
                        float ai = s_r[0][tid] + s_r[4][tid];
                        float ao = s_r[1][tid] + s_r[5][tid];
                        float au = s_r[2][tid] + s_r[6][tid];
                        float f1 = s_r[3][tid];
                        float f2 = s_r[7][tid];
                        int lc = P.left_idx[ctl], rc = P.right_idx[ctl];
                        float lh = P.h_buf[(size_t)lc * H + jo];
                        float rh = P.h_buf[(size_t)rc * H + jo];
                        float ii  = sigmoidf_(ai + P.bui[jo]);
                        float oo  = sigmoidf_(ao + P.buo[jo]);
                        float uu  = fmaxf(au + P.buu[jo], 0.f);
                        float ff1 = sigmoidf_(f1 + P.bf1[jo]);
                        float ff2 = sigmoidf_(f2 + P.bf2[jo]);
                        float cc  = ii * uu + ff1 * lh + ff2 * rh;
                        float h   = oo * fmaxf(cc, 0.f);
                        s_h[tid] = h;
                        P.h_buf[(size_t)c * H + jo] = h;
                    }
                    __syncthreads();
                } else {
                    // child h already materialized (leaves feeding level 1)
                    if (tid < 32) s_h[tid] = P.h_buf[(size_t)c * H + js + tid];
                    __syncthreads();
                }
                // FMA my register slice against the child h slice -> parent partial
                float r0 = 0.f, r1 = 0.f, r2 = 0.f, r3 = 0.f;
#pragma unroll
                for (int kk = 0; kk < 32; ++kk) {
                    float x = s_h[kk];
                    r0 = fmaf(x, w4[0][kk], r0);
                    r1 = fmaf(x, w4[1][kk], r1);
                    r2 = fmaf(x, w4[2][kk], r2);
                    r3 = fmaf(x, w4[3][kk], r3);
                }
                float* pn = P.part + (size_t)t * (64 * H) + (kt * 4) * H + tid;
                pn[0]     = r0;
                pn[H]     = r1;
                pn[2 * H] = r2;
                pn[3 * H] = r3;
                __syncthreads();
            }
            grid.sync();
            prev0 = tbase; prev1 = tbase + lvl;
            tbase += lvl;
            lvl >>= 1;
        }
    }

    // ================= final: root reduce + projection of all nodes =================
    const int root = P.n_nodes - 1;
    if (b == 0) {
        const int rt = root - P.n_leaves;
        const float* pc = P.part + (size_t)rt * (64 * H) + tid;
        float ai = 0.f, ao = 0.f, au = 0.f, f1 = 0.f, f2 = 0.f;
#pragma unroll
        for (int k2 = 0; k2 < 16; ++k2) {
            const float* q = pc + (size_t)k2 * 4 * H;
            ai += q[0];
            ao += q[H];
            au += q[2 * H];
            float fv = q[3 * H];
            if (k2 < 8) f1 += fv; else f2 += fv;
        }
        int lc = P.left_idx[rt], rc = P.right_idx[rt];
        float lh = P.h_buf[(size_t)lc * H + tid];
        float rh = P.h_buf[(size_t)rc * H + tid];
        float ii  = sigmoidf_(ai + P.bui[tid]);
        float oo  = sigmoidf_(ao + P.buo[tid]);
        float uu  = fmaxf(au + P.buu[tid], 0.f);
        float ff1 = sigmoidf_(f1 + P.bf1[tid]);
        float ff2 = sigmoidf_(f2 + P.bf2[tid]);
        float cc  = ii * uu + ff1 * lh + ff2 * rh;
        float h   = oo * fmaxf(cc, 0.f);
        P.h_buf[(size_t)root * H + tid] = h;
        proj_node(P, root, h, tid, s_red);
    }
    for (int n = b; n < root; n += G) {
        float h = P.h_buf[(size_t)n * H + tid];
        proj_node(P, n, h, tid, s_red);
    }
}

extern "C" void kernel_launch(void* const* d_in, const int* in_sizes, int n_in,
                              void* d_out, int out_size, void* d_ws, size_t ws_size,
                              hipStream_t stream)
{
    Params P;
    P.word_ids  = (const int*)d_in[0];
    P.left_idx  = (const int*)d_in[1];
    P.right_idx = (const int*)d_in[2];
    P.emb = (const float*)d_in[3];
    P.Wi  = (const float*)d_in[4];  P.bi  = (const float*)d_in[5];
    P.Wo  = (const float*)d_in[6];  P.bo  = (const float*)d_in[7];
    P.Wu  = (const float*)d_in[8];  P.bu  = (const float*)d_in[9];
    P.Ui  = (const float*)d_in[10]; P.bui = (const float*)d_in[11];
    P.Uo  = (const float*)d_in[12]; P.buo = (const float*)d_in[13];
    P.Uu  = (const float*)d_in[14]; P.buu = (const float*)d_in[15];
    P.Uf1 = (const float*)d_in[16]; P.bf1 = (const float*)d_in[17];
    P.Uf2 = (const float*)d_in[18]; P.bf2 = (const float*)d_in[19];
    P.Wp  = (const float*)d_in[20]; P.bp  = (const float*)d_in[21];
    P.n_leaves   = in_sizes[0];
    P.n_internal = in_sizes[1];
    P.n_nodes    = P.n_leaves + P.n_internal;
    P.out = (float*)d_out;
    (void)n_in; (void)out_size; (void)ws_size;

    float* ws = (float*)d_ws;
    P.h_buf = ws;
    P.part  = P.h_buf + (size_t)P.n_nodes * H;   // [n_internal][16][4][H]

    // adaptive cooperative grid size (host-side queries: capture-time only)
    int dev = 0;
    hipGetDevice(&dev);
    hipDeviceProp_t props;
    hipGetDeviceProperties(&props, dev);
    int perCU = 0;
    hipOccupancyMaxActiveBlocksPerMultiprocessor(&perCU, (const void*)tree_kernel, 256, 0);
    if (perCU < 1) perCU = 1;
    long Gl = (long)perCU * props.multiProcessorCount;
    int G = (Gl > 512) ? 512 : (int)Gl;
    G &= ~15;                 // multiple of 16 (covers the leaf phase's multiple-of-8)
    if (G < 16) G = 16;

    void* args[] = { &P };
    hipLaunchCooperativeKernel((void*)tree_kernel, dim3(G), dim3(256), args, 0, stream);
}

// Round 5
// 588.354 us; speedup vs baseline: 1.9219x; 1.1822x over previous
//
#include <hip/hip_runtime.h>
#include <hip/hip_cooperative_groups.h>
#include <math.h>

namespace cg = cooperative_groups;

#define H 256

struct Params {
    const int *word_ids, *left_idx, *right_idx;
    const float *emb;
    const float *Wi, *bi, *Wo, *bo, *Wu, *bu;
    const float *Ui, *bui, *Uo, *buo, *Uu, *buu;
    const float *Uf1, *bf1, *Uf2, *bf2, *Wp, *bp;
    float *h_buf;   // [n_nodes][H]
    float *out;     // [n_nodes][5]
    int n_leaves, n_internal, n_nodes;
};

__device__ __forceinline__ float sigmoidf_(float x) {
    return 1.0f / (1.0f + __expf(-x));
}

// Block layout: 512 threads = (j_local = tid>>5 in [0,16)) x (kc = tid&31 in [0,32)).
// Block b owns outputs j in [ (b&15)*16, (b&15)*16+16 ); cohort = b>>4 owns nodes
// idx = coh, coh+NCOH, ... of each level. No cross-block reduction anywhere.
__global__ __launch_bounds__(512, 4) void tree_kernel(Params P)
{
    cg::grid_group grid = cg::this_grid();
    const int tid  = threadIdx.x;
    const int b    = blockIdx.x;
    const int G    = gridDim.x;
    const int NCOH = G >> 4;
    const int coh  = b >> 4;
    const int jb   = (b & 15) * 16;
    const int kc   = tid & 31;
    const int j    = jb + (tid >> 5);

    __shared__ float s_cat[16][33];   // swizzled cat[512]: element k at [k&15][k>>4]
    __shared__ float s_e[8][33];      // swizzled emb row[256]: element k at [k&7][k>>3]
    __shared__ float s_red[8][5];

    // ================= leaf phase =================
    {
        float w0[8], w1[8], w2[8];
        {
            const float* pwi = P.Wi + (size_t)j * H + kc * 8;
            const float* pwo = P.Wo + (size_t)j * H + kc * 8;
            const float* pwu = P.Wu + (size_t)j * H + kc * 8;
#pragma unroll
            for (int kk = 0; kk < 8; ++kk) {
                w0[kk] = pwi[kk];
                w1[kk] = pwo[kk];
                w2[kk] = pwu[kk];
            }
        }
        const float bij = P.bi[j], boj = P.bo[j], buj = P.bu[j];

        int l = coh;
        float v = 0.f;
        if (l < P.n_leaves) {
            int wid = __builtin_amdgcn_readfirstlane(P.word_ids[l]);
            if (tid < 256) v = P.emb[(size_t)wid * H + tid];
        }
        for (; l < P.n_leaves; l += NCOH) {
            __syncthreads();
            if (tid < 256) s_e[tid & 7][tid >> 3] = v;
            // prefetch next leaf's embedding row
            int ln = l + NCOH;
            if (ln < P.n_leaves) {
                int wid = __builtin_amdgcn_readfirstlane(P.word_ids[ln]);
                if (tid < 256) v = P.emb[(size_t)wid * H + tid];
            }
            __syncthreads();
            float a0 = 0.f, a1 = 0.f, a2 = 0.f;
#pragma unroll
            for (int kk = 0; kk < 8; ++kk) {
                float x = s_e[kk][kc];
                a0 = fmaf(x, w0[kk], a0);
                a1 = fmaf(x, w1[kk], a1);
                a2 = fmaf(x, w2[kk], a2);
            }
#pragma unroll
            for (int m = 1; m <= 16; m <<= 1) {
                a0 += __shfl_xor(a0, m);
                a1 += __shfl_xor(a1, m);
                a2 += __shfl_xor(a2, m);
            }
            if (kc == 0) {
                float ii = sigmoidf_(a0 + bij);
                float oo = sigmoidf_(a1 + boj);
                float uu = fmaxf(a2 + buj, 0.f);
                float c  = ii * uu;
                float h  = oo * fmaxf(c, 0.f);
                P.h_buf[(size_t)l * H + j] = h;
            }
        }
    }
    grid.sync();

    // ================= internal levels =================
    {
        float w0[16], w1[16], w2[16], w3[16];
        {
            const float* pui = P.Ui + (size_t)j * 2 * H + kc * 16;
            const float* puo = P.Uo + (size_t)j * 2 * H + kc * 16;
            const float* puu = P.Uu + (size_t)j * 2 * H + kc * 16;
            const float* pf  = (kc < 16) ? (P.Uf1 + (size_t)j * H + kc * 16)
                                         : (P.Uf2 + (size_t)j * H + (kc - 16) * 16);
#pragma unroll
            for (int kk = 0; kk < 16; ++kk) {
                w0[kk] = pui[kk];
                w1[kk] = puo[kk];
                w2[kk] = puu[kk];
                w3[kk] = pf[kk];
            }
        }
        const float b_i = P.bui[j], b_o = P.buo[j], b_u = P.buu[j];
        const float b_1 = P.bf1[j], b_2 = P.bf2[j];

        int frontier = P.n_leaves;
        int tbase = 0;
        while (frontier > 1) {
            const int lvl = frontier >> 1;
            int idx = coh;
            float v = 0.f;
            if (idx < lvl) {
                int t  = tbase + idx;
                int lc = __builtin_amdgcn_readfirstlane(P.left_idx[t]);
                int rc = __builtin_amdgcn_readfirstlane(P.right_idx[t]);
                v = (tid < 256) ? P.h_buf[(size_t)lc * H + tid]
                                : P.h_buf[(size_t)rc * H + (tid - 256)];
            }
            for (; idx < lvl; idx += NCOH) {
                __syncthreads();
                s_cat[tid & 15][tid >> 4] = v;
                // prefetch next node's children h
                int idxn = idx + NCOH;
                if (idxn < lvl) {
                    int tn  = tbase + idxn;
                    int lcn = __builtin_amdgcn_readfirstlane(P.left_idx[tn]);
                    int rcn = __builtin_amdgcn_readfirstlane(P.right_idx[tn]);
                    v = (tid < 256) ? P.h_buf[(size_t)lcn * H + tid]
                                    : P.h_buf[(size_t)rcn * H + (tid - 256)];
                }
                __syncthreads();
                float a0 = 0.f, a1 = 0.f, a2 = 0.f, a3 = 0.f;
#pragma unroll
                for (int kk = 0; kk < 16; ++kk) {
                    float x = s_cat[kk][kc];
                    a0 = fmaf(x, w0[kk], a0);
                    a1 = fmaf(x, w1[kk], a1);
                    a2 = fmaf(x, w2[kk], a2);
                    a3 = fmaf(x, w3[kk], a3);
                }
#pragma unroll
                for (int m = 1; m <= 8; m <<= 1) {
                    a0 += __shfl_xor(a0, m);
                    a1 += __shfl_xor(a1, m);
                    a2 += __shfl_xor(a2, m);
                    a3 += __shfl_xor(a3, m);
                }
                float fo = __shfl_xor(a3, 16);
                a0 += __shfl_xor(a0, 16);
                a1 += __shfl_xor(a1, 16);
                a2 += __shfl_xor(a2, 16);
                if (kc == 0) {
                    const int t = tbase + idx;
                    float f1 = a3;      // lanes kc<16 hold f1 sum
                    float f2 = fo;      // partner half
                    float lh = s_cat[j & 15][j >> 4];
                    float rh = s_cat[j & 15][16 + (j >> 4)];
                    float ii  = sigmoidf_(a0 + b_i);
                    float oo  = sigmoidf_(a1 + b_o);
                    float uu  = fmaxf(a2 + b_u, 0.f);
                    float ff1 = sigmoidf_(f1 + b_1);
                    float ff2 = sigmoidf_(f2 + b_2);
                    float c   = ii * uu + ff1 * lh + ff2 * rh;
                    float h   = oo * fmaxf(c, 0.f);
                    P.h_buf[(size_t)(P.n_leaves + t) * H + j] = h;
                }
            }
            grid.sync();
            tbase += lvl;
            frontier = lvl + (frontier & 1);
        }
    }

    // ================= projection (all nodes) =================
    {
        float wp0 = 0.f, wp1 = 0.f, wp2 = 0.f, wp3 = 0.f, wp4 = 0.f;
        if (tid < 256) {
            wp0 = P.Wp[0 * H + tid];
            wp1 = P.Wp[1 * H + tid];
            wp2 = P.Wp[2 * H + tid];
            wp3 = P.Wp[3 * H + tid];
            wp4 = P.Wp[4 * H + tid];
        }
        for (int n = b; n < P.n_nodes; n += G) {
            float h = (tid < 256) ? P.h_buf[(size_t)n * H + tid] : 0.f;
            float p0 = wp0 * h, p1 = wp1 * h, p2 = wp2 * h, p3 = wp3 * h, p4 = wp4 * h;
#pragma unroll
            for (int m = 1; m <= 32; m <<= 1) {
                p0 += __shfl_xor(p0, m);
                p1 += __shfl_xor(p1, m);
                p2 += __shfl_xor(p2, m);
                p3 += __shfl_xor(p3, m);
                p4 += __shfl_xor(p4, m);
            }
            const int wv = tid >> 6;
            if ((tid & 63) == 0) {
                s_red[wv][0] = p0; s_red[wv][1] = p1; s_red[wv][2] = p2;
                s_red[wv][3] = p3; s_red[wv][4] = p4;
            }
            __syncthreads();
            if (tid < 5)
                P.out[(size_t)n * 5 + tid] = P.bp[tid]
                    + s_red[0][tid] + s_red[1][tid] + s_red[2][tid] + s_red[3][tid];
            __syncthreads();
        }
    }
}

extern "C" void kernel_launch(void* const* d_in, const int* in_sizes, int n_in,
                              void* d_out, int out_size, void* d_ws, size_t ws_size,
                              hipStream_t stream)
{
    Params P;
    P.word_ids  = (const int*)d_in[0];
    P.left_idx  = (const int*)d_in[1];
    P.right_idx = (const int*)d_in[2];
    P.emb = (const float*)d_in[3];
    P.Wi  = (const float*)d_in[4];  P.bi  = (const float*)d_in[5];
    P.Wo  = (const float*)d_in[6];  P.bo  = (const float*)d_in[7];
    P.Wu  = (const float*)d_in[8];  P.bu  = (const float*)d_in[9];
    P.Ui  = (const float*)d_in[10]; P.bui = (const float*)d_in[11];
    P.Uo  = (const float*)d_in[12]; P.buo = (const float*)d_in[13];
    P.Uu  = (const float*)d_in[14]; P.buu = (const float*)d_in[15];
    P.Uf1 = (const float*)d_in[16]; P.bf1 = (const float*)d_in[17];
    P.Uf2 = (const float*)d_in[18]; P.bf2 = (const float*)d_in[19];
    P.Wp  = (const float*)d_in[20]; P.bp  = (const float*)d_in[21];
    P.n_leaves   = in_sizes[0];
    P.n_internal = in_sizes[1];
    P.n_nodes    = P.n_leaves + P.n_internal;
    P.out = (float*)d_out;
    (void)n_in; (void)out_size; (void)ws_size;

    P.h_buf = (float*)d_ws;   // only n_nodes*H floats used

    // adaptive cooperative grid (host-side queries: capture-safe)
    int dev = 0;
    hipGetDevice(&dev);
    hipDeviceProp_t props;
    hipGetDeviceProperties(&props, dev);
    int perCU = 0;
    hipOccupancyMaxActiveBlocksPerMultiprocessor(&perCU, (const void*)tree_kernel, 512, 0);
    if (perCU < 1) perCU = 1;
    long Gl = (long)perCU * props.multiProcessorCount;
    int G = (Gl > 512) ? 512 : (int)Gl;
    G &= ~15;
    if (G < 16) G = 16;

    void* args[] = { &P };
    hipLaunchCooperativeKernel((void*)tree_kernel, dim3(G), dim3(512), args, 0, stream);
}